// Round 10
// baseline (25.406 us; speedup 1.0000x reference)
//
#include <hip/hip_runtime.h>
#include <math.h>

// HarmonicGenerator — SINGLE kernel, no workspace, no atomics, no memset.
// Grid (16 kg, 16 n) x 1024 threads. Each block:
//  P: prologue — w2l[c]=scale*ow (f64) by tid<256; SAB sums by the tail wave.
//  A: per-frame f64 stat chains (s, s^2, dot(x,w2)) over all 256 channels,
//     thread=(group g of 64 ch, frame t); mag dots (8 f32 chains) ONLY for
//     the block's 16-frame window [fbase, fbase+15].
//  B: combine -> channel-norm stats -> f0 (f64, exp2) -> Fl; window mags
//     -> 0.125*exp(min(z,6)) -> Mgl.
//  C: 200-region exclusive prefix scan (wave 0, f64) -> Tl.
//  D: evaluate 13 regions (4 concurrently via sub=tid>>8): recentered
//     phase polynomial tb(pc) = P' + S'*pc + Q*pc^2 (f64 setup, f32 eval),
//     per sample one v_fract+v_sin+v_cos, harmonics 2..8 by Chebyshev
//     recurrence, float4 stores.
// N=16, C=256, LF=200, SEG=960, Lw=192000, NH=8, SR=48000.

#define NB   16
#define CCH  256
#define LFR  200
#define LW   192000
#define NHH  8
#define NKM  201
#define RPB  13      // regions per block
#define NKG  16      // region groups: 16*13 = 208 >= 201
#define NF   16      // mag frame window per block
#define INV_SR (1.0 / 48000.0)

__device__ inline double wave_sum64(double v) {
    #pragma unroll
    for (int off = 32; off > 0; off >>= 1) v += __shfl_xor(v, off);
    return v;
}
__device__ inline double wave_incl_scan64(double v) {
    int lane = threadIdx.x & 63;
    #pragma unroll
    for (int off = 1; off < 64; off <<= 1) {
        double t = __shfl_up(v, off);
        if (lane >= off) v += t;
    }
    return v;
}

__global__ __launch_bounds__(1024)
void hg_all(const float* __restrict__ x,
            const float* __restrict__ mag_w, const float* __restrict__ mag_b,
            const float* __restrict__ cn_scale, const float* __restrict__ cn_shift,
            const float* __restrict__ oct_w, const float* __restrict__ oct_b,
            float* __restrict__ out) {
    __shared__ double w2l[CCH];
    __shared__ double psum[4][256], psumsq[4][256], pdotx[4][256];
    __shared__ float  pmag[4][NF][NHH];
    __shared__ double Fl[LFR];
    __shared__ double Tl[LFR];
    __shared__ float  Mgl[NF][NHH];
    __shared__ double SAB[2];

    int kg = blockIdx.x, n = blockIdx.y;
    int tid = threadIdx.x;
    int t = tid & 255;          // frame slot
    int g = tid >> 8;           // channel group (64 ch each)
    int fbase = max(kg * RPB - 1, 0);

    // ---- P: prologue ----
    if (tid < CCH)
        w2l[tid] = (double)cn_scale[tid] * (double)oct_w[tid];
    if (tid >= 960) {           // tail wave: SAB (independent of w2l)
        int lane = tid & 63;
        double sa = 0.0, sb = 0.0;
        #pragma unroll
        for (int k = 0; k < 4; k++) {
            int c = lane + 64 * k;
            double ow = (double)oct_w[c];
            sa = fma((double)cn_scale[c], ow, sa);
            sb = fma((double)cn_shift[c], ow, sb);
        }
        sa = wave_sum64(sa);
        sb = wave_sum64(sb);
        if (lane == 0) { SAB[0] = sa; SAB[1] = sb; }
    }
    __syncthreads();

    // ---- A: stat chains (all frames) + mag dots (window frames only) ----
    int gs = __builtin_amdgcn_readfirstlane(g);
    const float* xb = x + (size_t)n * CCH * LFR;
    int nf = t - fbase;
    bool needmag = (t < LFR) && ((unsigned)nf < (unsigned)NF);

    double s = 0.0, s2 = 0.0, dx = 0.0;
    float zm[NHH] = {0.f, 0.f, 0.f, 0.f, 0.f, 0.f, 0.f, 0.f};
    #pragma unroll 4
    for (int cc = 0; cc < 64; cc++) {
        int c = gs * 64 + cc;
        float xf = (t < LFR) ? xb[(size_t)c * LFR + t] : 0.f;
        double xd = (double)xf;
        s  += xd;
        s2  = fma(xd, xd, s2);
        dx  = fma(xd, w2l[c], dx);
        if (needmag) {
            #pragma unroll
            for (int h = 0; h < NHH; h++)
                zm[h] = fmaf(xf, mag_w[h * CCH + c], zm[h]);
        }
    }
    psum[g][t] = s; psumsq[g][t] = s2; pdotx[g][t] = dx;
    if (needmag) {
        #pragma unroll
        for (int h = 0; h < NHH; h++) pmag[g][nf][h] = zm[h];
    }
    __syncthreads();

    // ---- B: stats -> f0 (threads 0..199); window mags (threads 256..383) ----
    if (tid < LFR) {
        double s_  = psum[0][tid] + psum[1][tid] + psum[2][tid] + psum[3][tid];
        double s2_ = psumsq[0][tid] + psumsq[1][tid] + psumsq[2][tid] + psumsq[3][tid];
        double dx_ = pdotx[0][tid] + pdotx[1][tid] + pdotx[2][tid] + pdotx[3][tid];
        double mu  = s_ * (1.0 / 256.0);
        double var = (s2_ - s_ * mu) * (1.0 / 255.0);
        double inv = 1.0 / (sqrt(var) + 1e-4);          // unbiased std + EPS
        double oct = inv * (dx_ - mu * SAB[0]) + SAB[1] + (double)oct_b[0];
        double f0  = 440.0 * exp2(oct);
        Fl[tid] = fmin(fmax(f0, 20.0), 16000.0);
    }
    if (tid >= 256 && tid < 256 + NF * NHH) {
        int q = tid - 256;
        int w = q >> 3, h = q & 7;
        float z = pmag[0][w][h] + pmag[1][w][h] + pmag[2][w][h] + pmag[3][w][h]
                + mag_b[h];
        Mgl[w][h] = 0.125f * expf(fminf(z, 6.f));       // fold 1/8 mean
    }
    __syncthreads();

    // ---- C: exclusive scan (wave 0): Tl[k] = 480*F[0] + sum_{i<k} 480*(F[i]+F[i+1])
    if (tid < 64) {
        double carry = 480.0 * Fl[0];
        for (int base = 0; base < LFR; base += 64) {
            int k = base + tid;
            double d = (k < LFR - 1) ? 480.0 * (Fl[k] + Fl[k + 1]) : 0.0;
            double scn = wave_incl_scan64(d);
            if (k < LFR) Tl[k] = carry + scn - d;
            carry += __shfl(scn, 63);
        }
    }
    __syncthreads();

    // ---- D: evaluate regions; 4 concurrent sub-blocks ----
    int sub = tid >> 8;
    int tt  = tid & 255;
    for (int i = sub; i < RPB; i += 4) {
        int km = kg * RPB + i;
        if (km >= NKM) continue;
        int kc = min(max(km - 1, 0), LFR - 1);
        bool body = (km >= 1 && km <= LFR - 1);
        double Sd = Fl[kc] * INV_SR;
        double Qd = body ? (Fl[km] - Fl[km - 1]) * (INV_SR / 1920.0) : 0.0;
        double Pd = (km == 0) ? (-480.0 * Fl[0] * INV_SR) : Tl[km - 1] * INV_SR;
        double Pp = Pd + 480.0 * Sd + 230400.0 * Qd;    // recenter at midpoint
        double Sp = Sd + 960.0 * Qd;
        float Pf = (float)(Pp - floor(Pp));
        float Sf = (float)Sp;
        float Qf = (float)Qd;
        int nfc = kc - fbase;                            // in [0, NF)
        float ma[NHH], md[NHH];
        #pragma unroll
        for (int h = 0; h < NHH; h++) {
            float a = Mgl[nfc][h];
            ma[h] = a;
            md[h] = body ? (Mgl[km - fbase][h] - a) : 0.f;
        }

        if (tt < 240) {
            int j0 = 960 * km - 480 + tt * 4;
            if (j0 >= 0 && j0 < LW) {
                float r[4];
                #pragma unroll
                for (int u = 0; u < 4; u++) {
                    float pc = (float)(tt * 4 - 479 + u);      // [-479, 480]
                    float tb = fmaf(pc, fmaf(Qf, pc, Sf), Pf); // phase (cycles)
                    float fr, s1, c1;
                    asm("v_fract_f32 %0, %1" : "=v"(fr) : "v"(tb));
                    asm("v_sin_f32 %0, %1" : "=v"(s1) : "v"(fr));
                    asm("v_cos_f32 %0, %1" : "=v"(c1) : "v"(fr));
                    float twoc = c1 + c1;
                    float w = (pc + 479.5f) * (1.0f / 960.0f);
                    float sp = 0.f, sc = s1;                   // Chebyshev
                    float acc = 0.f;
                    #pragma unroll
                    for (int h = 0; h < NHH; h++) {
                        acc = fmaf(fmaf(md[h], w, ma[h]), sc, acc);
                        float sn = fmaf(twoc, sc, -sp);
                        sp = sc; sc = sn;
                    }
                    r[u] = acc;
                }
                *(float4*)(out + (size_t)n * LW + j0) =
                    make_float4(r[0], r[1], r[2], r[3]);
            }
        }
    }
}

extern "C" void kernel_launch(void* const* d_in, const int* in_sizes, int n_in,
                              void* d_out, int out_size, void* d_ws, size_t ws_size,
                              hipStream_t stream) {
    const float* x        = (const float*)d_in[0];
    const float* mag_w    = (const float*)d_in[1];
    const float* mag_b    = (const float*)d_in[2];
    const float* cn_scale = (const float*)d_in[3];
    const float* cn_shift = (const float*)d_in[4];
    const float* oct_w    = (const float*)d_in[5];
    const float* oct_b    = (const float*)d_in[6];
    float* out = (float*)d_out;

    hg_all<<<dim3(NKG, NB), dim3(1024), 0, stream>>>(
        x, mag_w, mag_b, cn_scale, cn_shift, oct_w, oct_b, out);
}

// Round 11
// 24.348 us; speedup vs baseline: 1.0434x; 1.0434x over previous
//
#include <hip/hip_runtime.h>
#include <math.h>

// HarmonicGenerator: closed-form piecewise-linear cumsum. 3 lean kernels,
// no atomics, no memset (R5 structure — best measured — with trims).
// K1 hg_partial: (NB x CG=16) blocks; per-frame partial sums over 16
//   channels each (coalesced; f64 chains for norm/octave, f32 mag dots).
// K2 hg_tables: 16 blocks; combine -> stats -> f0 (f64) -> prefix scan ->
//   per-region f32 params {frac(P'), S', Q, 0.125*magA[8], 0.125*magD[8]}
//   (phase polynomial recentered at region midpoint).
// K3 hg_wave: 4 tiles/block; pure f32; per sample one v_fract+v_sin+v_cos,
//   harmonics 2..8 via Chebyshev recurrence; float4 stores.
// N=16, C=256, LF=200, SEG=960, Lw=192000, NH=8, SR=48000.

#define NB   16
#define CCH  256
#define LFR  200
#define LW   192000
#define NHH  8
#define NKM  201
#define NT   (NB * NKM)     // 3216 tiles
#define CG   16             // partial blocks per n
#define CPB  16             // channels per partial block
#define INV_SR (1.0 / 48000.0)
#define PSTRIDE 20          // floats per (n,km) param record
#define TPB  4              // tiles per wave-kernel block

__device__ inline double wave_sum64(double v) {
    #pragma unroll
    for (int off = 32; off > 0; off >>= 1) v += __shfl_xor(v, off);
    return v;
}
__device__ inline double wave_incl_scan64(double v) {
    int lane = threadIdx.x & 63;
    #pragma unroll
    for (int off = 1; off < 64; off <<= 1) {
        double t = __shfl_up(v, off);
        if (lane >= off) v += t;
    }
    return v;
}

// K1: partial sums. Thread = frame slot t; loops CPB channels (uniform c ->
// scalar weight loads, coalesced x loads across t).
__global__ __launch_bounds__(256)
void hg_partial(const float* __restrict__ x,
                const float* __restrict__ mag_w,
                const float* __restrict__ cn_scale,
                const float* __restrict__ oct_w,
                double* __restrict__ ps, double* __restrict__ ps2,
                double* __restrict__ pdx, float* __restrict__ pmg) {
    int n = blockIdx.x, cg = blockIdx.y;
    int t = threadIdx.x;
    const float* xb = x + (size_t)n * CCH * LFR;
    int cbase = cg * CPB;

    double s = 0.0, s2 = 0.0, dx = 0.0;
    float zm[NHH] = {0.f, 0.f, 0.f, 0.f, 0.f, 0.f, 0.f, 0.f};
    #pragma unroll
    for (int cc = 0; cc < CPB; cc++) {
        int c = cbase + cc;
        float xf = (t < LFR) ? xb[(size_t)c * LFR + t] : 0.f;
        double xd = (double)xf;
        double w2 = (double)cn_scale[c] * (double)oct_w[c];
        s += xd;
        s2 = fma(xd, xd, s2);
        dx = fma(xd, w2, dx);
        #pragma unroll
        for (int h = 0; h < NHH; h++)
            zm[h] = fmaf(xf, mag_w[h * CCH + c], zm[h]);
    }
    size_t pi = ((size_t)n * CG + cg) * 256 + t;
    ps[pi] = s; ps2[pi] = s2; pdx[pi] = dx;
    #pragma unroll
    for (int h = 0; h < NHH; h++)
        pmg[(((size_t)n * CG + cg) * NHH + h) * 256 + t] = zm[h];
}

// K2: per-n combine + stats + scan + tables.
__global__ __launch_bounds__(256)
void hg_tables(const double* __restrict__ ps, const double* __restrict__ ps2,
               const double* __restrict__ pdx, const float* __restrict__ pmg,
               const float* __restrict__ mag_b,
               const float* __restrict__ cn_scale, const float* __restrict__ cn_shift,
               const float* __restrict__ oct_w, const float* __restrict__ oct_b,
               float* __restrict__ params) {
    __shared__ double Fl[LFR];
    __shared__ double Tl[LFR];
    __shared__ float  Mgl[LFR][NHH];
    __shared__ double SAB[2];

    int n = blockIdx.x, tid = threadIdx.x;

    // SA = sum(scale*ow), SB = sum(shift*ow)  (wave 0, f64)
    if (tid < 64) {
        double sa = 0.0, sb = 0.0;
        #pragma unroll
        for (int k = 0; k < 4; k++) {
            int c = tid + 64 * k;
            double ow = (double)oct_w[c];
            sa = fma((double)cn_scale[c], ow, sa);
            sb = fma((double)cn_shift[c], ow, sb);
        }
        sa = wave_sum64(sa);
        sb = wave_sum64(sb);
        if (tid == 0) { SAB[0] = sa; SAB[1] = sb; }
    }
    __syncthreads();

    if (tid < LFR) {
        double s = 0.0, s2 = 0.0, dx = 0.0;
        #pragma unroll
        for (int cg = 0; cg < CG; cg++) {
            size_t pi = ((size_t)n * CG + cg) * 256 + tid;
            s += ps[pi]; s2 += ps2[pi]; dx += pdx[pi];
        }
        double mu  = s * (1.0 / 256.0);
        double var = (s2 - s * mu) * (1.0 / 255.0);
        double inv = 1.0 / (sqrt(var) + 1e-4);          // unbiased std + EPS
        double oct = inv * (dx - mu * SAB[0]) + SAB[1] + (double)oct_b[0];
        double f0  = 440.0 * exp2(oct);
        Fl[tid] = fmin(fmax(f0, 20.0), 16000.0);
        #pragma unroll
        for (int h = 0; h < NHH; h++) {
            float z = 0.f;
            #pragma unroll
            for (int cg = 0; cg < CG; cg++)
                z += pmg[(((size_t)n * CG + cg) * NHH + h) * 256 + tid];
            Mgl[tid][h] = 0.125f * expf(fminf(z + mag_b[h], 6.f));  // fold mean
        }
    }
    __syncthreads();

    // exclusive scan: Tl[k] = 480*F[0] + sum_{i<k} 480*(F[i]+F[i+1])
    if (tid < 64) {
        double carry = 480.0 * Fl[0];
        for (int base = 0; base < LFR; base += 64) {
            int k = base + tid;
            double d = (k < LFR - 1) ? 480.0 * (Fl[k] + Fl[k + 1]) : 0.0;
            double scn = wave_incl_scan64(d);
            if (k < LFR) Tl[k] = carry + scn - d;
            carry += __shfl(scn, 63);
        }
    }
    __syncthreads();

    // params, recentered: tb(pc) = P' + S'*pc + Q*pc^2, pc in [-479,480]
    if (tid < NKM) {
        int km = tid;
        int kc = min(max(km - 1, 0), LFR - 1);
        bool body = (km >= 1 && km <= LFR - 1);
        double Sd = Fl[kc] * INV_SR;
        double Qd = body ? (Fl[km] - Fl[km - 1]) * (INV_SR / 1920.0) : 0.0;
        double Pd = (km == 0) ? (-480.0 * Fl[0] * INV_SR) : Tl[km - 1] * INV_SR;
        double Pp = Pd + 480.0 * Sd + 230400.0 * Qd;
        double Sp = Sd + 960.0 * Qd;
        float* pr = params + ((size_t)n * NKM + km) * PSTRIDE;
        pr[0] = (float)(Pp - floor(Pp));
        pr[1] = (float)Sp;
        pr[2] = (float)Qd;
        pr[3] = 0.f;
        #pragma unroll
        for (int h = 0; h < NHH; h++) {
            float a = Mgl[kc][h];
            pr[4 + h]  = a;
            pr[12 + h] = body ? (Mgl[km][h] - a) : 0.f;
        }
    }
}

// K3: 4 tiles (km,n) per block; 4 consecutive samples/thread per tile.
// Chebyshev: s_{h+1} = 2*cos(2*pi*f)*s_h - s_{h-1}.
__global__ __launch_bounds__(256)
void hg_wave(const float* __restrict__ params, float* __restrict__ out) {
    int tid = threadIdx.x;
    #pragma unroll
    for (int i = 0; i < TPB; i++) {
        int tile = blockIdx.x * TPB + i;               // 0..3215
        int n = tile / NKM, km = tile - n * NKM;
        const float4* pb = (const float4*)(params + (size_t)tile * PSTRIDE);
        float4 v0 = pb[0], v1 = pb[1], v2 = pb[2], v3 = pb[3], v4 = pb[4];
        float Pf = v0.x, Sf = v0.y, Qf = v0.z;
        float ma[NHH] = {v1.x, v1.y, v1.z, v1.w, v2.x, v2.y, v2.z, v2.w};
        float md[NHH] = {v3.x, v3.y, v3.z, v3.w, v4.x, v4.y, v4.z, v4.w};

        if (tid >= 240) continue;
        int j0 = 960 * km - 480 + tid * 4;
        if (j0 < 0 || j0 >= LW) continue;              // clipped head/tail

        float r[4];
        #pragma unroll
        for (int u = 0; u < 4; u++) {
            float pc = (float)(tid * 4 - 479 + u);     // [-479, 480]
            float tb = fmaf(pc, fmaf(Qf, pc, Sf), Pf); // phase (cycles)
            float fr, s1, c1;
            asm("v_fract_f32 %0, %1" : "=v"(fr) : "v"(tb));
            asm("v_sin_f32 %0, %1" : "=v"(s1) : "v"(fr));
            asm("v_cos_f32 %0, %1" : "=v"(c1) : "v"(fr));
            float twoc = c1 + c1;
            float w = (pc + 479.5f) * (1.0f / 960.0f);
            float sp = 0.f, sc = s1;                   // s_0, s_1
            float acc = 0.f;
            #pragma unroll
            for (int h = 0; h < NHH; h++) {
                acc = fmaf(fmaf(md[h], w, ma[h]), sc, acc);
                float sn = fmaf(twoc, sc, -sp);
                sp = sc; sc = sn;
            }
            r[u] = acc;
        }
        *(float4*)(out + (size_t)n * LW + j0) = make_float4(r[0], r[1], r[2], r[3]);
    }
}

extern "C" void kernel_launch(void* const* d_in, const int* in_sizes, int n_in,
                              void* d_out, int out_size, void* d_ws, size_t ws_size,
                              hipStream_t stream) {
    const float* x        = (const float*)d_in[0];
    const float* mag_w    = (const float*)d_in[1];
    const float* mag_b    = (const float*)d_in[2];
    const float* cn_scale = (const float*)d_in[3];
    const float* cn_shift = (const float*)d_in[4];
    const float* oct_w    = (const float*)d_in[5];
    const float* oct_b    = (const float*)d_in[6];
    float* out = (float*)d_out;

    // ws: ps|ps2|pdx f64[NB*CG*256] each | pmg f32[NB*CG*8*256] | params f32
    double* ps  = (double*)d_ws;
    double* ps2 = ps  + (size_t)NB * CG * 256;
    double* pdx = ps2 + (size_t)NB * CG * 256;
    float*  pmg = (float*)(pdx + (size_t)NB * CG * 256);
    float*  params = pmg + (size_t)NB * CG * NHH * 256;

    hg_partial<<<dim3(NB, CG), dim3(256), 0, stream>>>(
        x, mag_w, cn_scale, oct_w, ps, ps2, pdx, pmg);
    hg_tables<<<dim3(NB), dim3(256), 0, stream>>>(
        ps, ps2, pdx, pmg, mag_b, cn_scale, cn_shift, oct_w, oct_b, params);
    hg_wave<<<dim3(NT / TPB), dim3(256), 0, stream>>>(params, out);
}

// Round 12
// 22.579 us; speedup vs baseline: 1.1252x; 1.0784x over previous
//
#include <hip/hip_runtime.h>
#include <math.h>

// HarmonicGenerator: closed-form piecewise-linear cumsum. 3 lean kernels,
// no atomics, no memset. Exact R5 structure (best measured: 22.8us) with
// strictly-work-reducing trims (LDS w2 precompute; 0.125 fold in params).
// K1 hg_partial: (NB x CG=8) blocks; per-frame partial sums over 32
//   channels each (coalesced; f64 chains for norm/octave, f32 mag dots).
// K2 hg_tables: 16 blocks; combine -> stats -> f0 (f64) -> prefix scan ->
//   per-region f32 params {frac(P'), S', Q, 0.125*magA[8], 0.125*magD[8]}
//   (phase polynomial recentered at region midpoint).
// K3 hg_wave: 4 tiles/block; pure f32; per sample one v_fract+v_sin+v_cos,
//   harmonics 2..8 via Chebyshev recurrence; float4 stores.
// N=16, C=256, LF=200, SEG=960, Lw=192000, NH=8, SR=48000.

#define NB   16
#define CCH  256
#define LFR  200
#define LW   192000
#define NHH  8
#define NKM  201
#define NT   (NB * NKM)     // 3216 tiles
#define CG   8              // partial blocks per n
#define CPB  32             // channels per partial block
#define INV_SR (1.0 / 48000.0)
#define PSTRIDE 20          // floats per (n,km) param record
#define TPB  4              // tiles per wave-kernel block

__device__ inline double wave_sum64(double v) {
    #pragma unroll
    for (int off = 32; off > 0; off >>= 1) v += __shfl_xor(v, off);
    return v;
}
__device__ inline double wave_incl_scan64(double v) {
    int lane = threadIdx.x & 63;
    #pragma unroll
    for (int off = 1; off < 64; off <<= 1) {
        double t = __shfl_up(v, off);
        if (lane >= off) v += t;
    }
    return v;
}

// K1: partial sums. Thread = frame slot t; loops CPB channels (uniform c ->
// scalar weight loads, coalesced x loads across t). w2 precomputed in LDS.
__global__ __launch_bounds__(256)
void hg_partial(const float* __restrict__ x,
                const float* __restrict__ mag_w,
                const float* __restrict__ cn_scale,
                const float* __restrict__ oct_w,
                double* __restrict__ ps, double* __restrict__ ps2,
                double* __restrict__ pdx, float* __restrict__ pmg) {
    __shared__ double w2l[CPB];
    int n = blockIdx.x, cg = blockIdx.y;
    int t = threadIdx.x;
    const float* xb = x + (size_t)n * CCH * LFR;
    int cbase = cg * CPB;

    if (t < CPB)
        w2l[t] = (double)cn_scale[cbase + t] * (double)oct_w[cbase + t];
    __syncthreads();

    double s = 0.0, s2 = 0.0, dx = 0.0;
    float zm[NHH] = {0.f, 0.f, 0.f, 0.f, 0.f, 0.f, 0.f, 0.f};
    #pragma unroll 8
    for (int cc = 0; cc < CPB; cc++) {
        int c = cbase + cc;
        float xf = (t < LFR) ? xb[(size_t)c * LFR + t] : 0.f;
        double xd = (double)xf;
        s += xd;
        s2 = fma(xd, xd, s2);
        dx = fma(xd, w2l[cc], dx);
        #pragma unroll
        for (int h = 0; h < NHH; h++)
            zm[h] = fmaf(xf, mag_w[h * CCH + c], zm[h]);
    }
    size_t pi = ((size_t)n * CG + cg) * 256 + t;
    ps[pi] = s; ps2[pi] = s2; pdx[pi] = dx;
    #pragma unroll
    for (int h = 0; h < NHH; h++)
        pmg[(((size_t)n * CG + cg) * NHH + h) * 256 + t] = zm[h];
}

// K2: per-n combine + stats + scan + tables.
__global__ __launch_bounds__(256)
void hg_tables(const double* __restrict__ ps, const double* __restrict__ ps2,
               const double* __restrict__ pdx, const float* __restrict__ pmg,
               const float* __restrict__ mag_b,
               const float* __restrict__ cn_scale, const float* __restrict__ cn_shift,
               const float* __restrict__ oct_w, const float* __restrict__ oct_b,
               float* __restrict__ params) {
    __shared__ double Fl[LFR];
    __shared__ double Tl[LFR];
    __shared__ float  Mgl[LFR][NHH];
    __shared__ double SAB[2];

    int n = blockIdx.x, tid = threadIdx.x;

    // SA = sum(scale*ow), SB = sum(shift*ow)  (wave 0, f64)
    if (tid < 64) {
        double sa = 0.0, sb = 0.0;
        #pragma unroll
        for (int k = 0; k < 4; k++) {
            int c = tid + 64 * k;
            double ow = (double)oct_w[c];
            sa = fma((double)cn_scale[c], ow, sa);
            sb = fma((double)cn_shift[c], ow, sb);
        }
        sa = wave_sum64(sa);
        sb = wave_sum64(sb);
        if (tid == 0) { SAB[0] = sa; SAB[1] = sb; }
    }
    __syncthreads();

    if (tid < LFR) {
        double s = 0.0, s2 = 0.0, dx = 0.0;
        #pragma unroll
        for (int cg = 0; cg < CG; cg++) {
            size_t pi = ((size_t)n * CG + cg) * 256 + tid;
            s += ps[pi]; s2 += ps2[pi]; dx += pdx[pi];
        }
        double mu  = s * (1.0 / 256.0);
        double var = (s2 - s * mu) * (1.0 / 255.0);
        double inv = 1.0 / (sqrt(var) + 1e-4);          // unbiased std + EPS
        double oct = inv * (dx - mu * SAB[0]) + SAB[1] + (double)oct_b[0];
        double f0  = 440.0 * exp2(oct);
        Fl[tid] = fmin(fmax(f0, 20.0), 16000.0);
        #pragma unroll
        for (int h = 0; h < NHH; h++) {
            float z = 0.f;
            #pragma unroll
            for (int cg = 0; cg < CG; cg++)
                z += pmg[(((size_t)n * CG + cg) * NHH + h) * 256 + tid];
            Mgl[tid][h] = 0.125f * expf(fminf(z + mag_b[h], 6.f));  // fold mean
        }
    }
    __syncthreads();

    // exclusive scan: Tl[k] = 480*F[0] + sum_{i<k} 480*(F[i]+F[i+1])
    if (tid < 64) {
        double carry = 480.0 * Fl[0];
        for (int base = 0; base < LFR; base += 64) {
            int k = base + tid;
            double d = (k < LFR - 1) ? 480.0 * (Fl[k] + Fl[k + 1]) : 0.0;
            double scn = wave_incl_scan64(d);
            if (k < LFR) Tl[k] = carry + scn - d;
            carry += __shfl(scn, 63);
        }
    }
    __syncthreads();

    // params, recentered: tb(pc) = P' + S'*pc + Q*pc^2, pc in [-479,480]
    if (tid < NKM) {
        int km = tid;
        int kc = min(max(km - 1, 0), LFR - 1);
        bool body = (km >= 1 && km <= LFR - 1);
        double Sd = Fl[kc] * INV_SR;
        double Qd = body ? (Fl[km] - Fl[km - 1]) * (INV_SR / 1920.0) : 0.0;
        double Pd = (km == 0) ? (-480.0 * Fl[0] * INV_SR) : Tl[km - 1] * INV_SR;
        double Pp = Pd + 480.0 * Sd + 230400.0 * Qd;
        double Sp = Sd + 960.0 * Qd;
        float* pr = params + ((size_t)n * NKM + km) * PSTRIDE;
        pr[0] = (float)(Pp - floor(Pp));
        pr[1] = (float)Sp;
        pr[2] = (float)Qd;
        pr[3] = 0.f;
        #pragma unroll
        for (int h = 0; h < NHH; h++) {
            float a = Mgl[kc][h];
            pr[4 + h]  = a;
            pr[12 + h] = body ? (Mgl[km][h] - a) : 0.f;
        }
    }
}

// K3: 4 tiles (km,n) per block; 4 consecutive samples/thread per tile.
// Chebyshev: s_{h+1} = 2*cos(2*pi*f)*s_h - s_{h-1}.
__global__ __launch_bounds__(256)
void hg_wave(const float* __restrict__ params, float* __restrict__ out) {
    int tid = threadIdx.x;
    #pragma unroll
    for (int i = 0; i < TPB; i++) {
        int tile = blockIdx.x * TPB + i;               // 0..3215
        int n = tile / NKM, km = tile - n * NKM;
        const float4* pb = (const float4*)(params + (size_t)tile * PSTRIDE);
        float4 v0 = pb[0], v1 = pb[1], v2 = pb[2], v3 = pb[3], v4 = pb[4];
        float Pf = v0.x, Sf = v0.y, Qf = v0.z;
        float ma[NHH] = {v1.x, v1.y, v1.z, v1.w, v2.x, v2.y, v2.z, v2.w};
        float md[NHH] = {v3.x, v3.y, v3.z, v3.w, v4.x, v4.y, v4.z, v4.w};

        if (tid >= 240) continue;
        int j0 = 960 * km - 480 + tid * 4;
        if (j0 < 0 || j0 >= LW) continue;              // clipped head/tail

        float r[4];
        #pragma unroll
        for (int u = 0; u < 4; u++) {
            float pc = (float)(tid * 4 - 479 + u);     // [-479, 480]
            float tb = fmaf(pc, fmaf(Qf, pc, Sf), Pf); // phase (cycles)
            float fr, s1, c1;
            asm("v_fract_f32 %0, %1" : "=v"(fr) : "v"(tb));
            asm("v_sin_f32 %0, %1" : "=v"(s1) : "v"(fr));
            asm("v_cos_f32 %0, %1" : "=v"(c1) : "v"(fr));
            float twoc = c1 + c1;
            float w = (pc + 479.5f) * (1.0f / 960.0f);
            float sp = 0.f, sc = s1;                   // s_0, s_1
            float acc = 0.f;
            #pragma unroll
            for (int h = 0; h < NHH; h++) {
                acc = fmaf(fmaf(md[h], w, ma[h]), sc, acc);
                float sn = fmaf(twoc, sc, -sp);
                sp = sc; sc = sn;
            }
            r[u] = acc;
        }
        *(float4*)(out + (size_t)n * LW + j0) = make_float4(r[0], r[1], r[2], r[3]);
    }
}

extern "C" void kernel_launch(void* const* d_in, const int* in_sizes, int n_in,
                              void* d_out, int out_size, void* d_ws, size_t ws_size,
                              hipStream_t stream) {
    const float* x        = (const float*)d_in[0];
    const float* mag_w    = (const float*)d_in[1];
    const float* mag_b    = (const float*)d_in[2];
    const float* cn_scale = (const float*)d_in[3];
    const float* cn_shift = (const float*)d_in[4];
    const float* oct_w    = (const float*)d_in[5];
    const float* oct_b    = (const float*)d_in[6];
    float* out = (float*)d_out;

    // ws: ps|ps2|pdx f64[NB*CG*256] each | pmg f32[NB*CG*8*256] | params f32
    double* ps  = (double*)d_ws;
    double* ps2 = ps  + (size_t)NB * CG * 256;
    double* pdx = ps2 + (size_t)NB * CG * 256;
    float*  pmg = (float*)(pdx + (size_t)NB * CG * 256);
    float*  params = pmg + (size_t)NB * CG * NHH * 256;

    hg_partial<<<dim3(NB, CG), dim3(256), 0, stream>>>(
        x, mag_w, cn_scale, oct_w, ps, ps2, pdx, pmg);
    hg_tables<<<dim3(NB), dim3(256), 0, stream>>>(
        ps, ps2, pdx, pmg, mag_b, cn_scale, cn_shift, oct_w, oct_b, params);
    hg_wave<<<dim3(NT / TPB), dim3(256), 0, stream>>>(params, out);
}